// Round 13
// baseline (129.941 us; speedup 1.0000x reference)
//
#include <hip/hip_runtime.h>
#include <hip/hip_bf16.h>
#include <cstdint>
#include <cstddef>

typedef __attribute__((ext_vector_type(8))) short short8;
typedef __attribute__((ext_vector_type(4))) float f32x4;

static constexpr int M_TOT = 31744;
static constexpr int N_TOT = 1152;
static constexpr int K_TOT = 768;
static constexpr long A_ELEMS = (long)M_TOT * K_TOT;   // 24379392
static constexpr long W_ELEMS = (long)N_TOT * K_TOT;   // 884736
static constexpr int CYC_ROWS = 3968;                  // one ragged cycle (4 images)

__device__ __forceinline__ unsigned short f2bf(float f) {
  unsigned int u = __float_as_uint(f);
  u += 0x7FFFu + ((u >> 16) & 1u);   // round-to-nearest-even
  return (unsigned short)(u >> 16);
}
__device__ __forceinline__ float bf2f(unsigned short u) {
  return __uint_as_float((unsigned int)u << 16);
}

// ---------------- pass 1: fp32 -> bf16 for A (seq_patches) and W ----------------
__global__ void cvt_kernel(const float* __restrict__ A, const float* __restrict__ W,
                           unsigned short* __restrict__ dst) {
  long chunk = (long)blockIdx.x * blockDim.x + threadIdx.x;  // one chunk = 8 floats
  long i = chunk * 8;
  const float* src = (i < A_ELEMS) ? (A + i) : (W + (i - A_ELEMS));
  float4 v0 = *(const float4*)(src);
  float4 v1 = *(const float4*)(src + 4);
  short8 o;
  o[0] = (short)f2bf(v0.x); o[1] = (short)f2bf(v0.y);
  o[2] = (short)f2bf(v0.z); o[3] = (short)f2bf(v0.w);
  o[4] = (short)f2bf(v1.x); o[5] = (short)f2bf(v1.y);
  o[6] = (short)f2bf(v1.z); o[7] = (short)f2bf(v1.w);
  *(short8*)(dst + i) = o;
}

// ---------------- pass 1b: pos table  tab[rem,d] = bf16(bias[d] + bilinear(pos)[rem,d]) ----
__global__ void tab_kernel(const float* __restrict__ pos, const float* __restrict__ bias,
                           unsigned short* __restrict__ tab) {
  const int t = blockIdx.x * blockDim.x + threadIdx.x;   // 571392 = 3968 * 144
  const int row = t / 144;
  const int dc = (t - row * 144) * 8;

  int rr, cc; float sy, sx;
  if (row < 1024)      { rr = row >> 5; cc = row & 31; sy = 0.5f;         sx = 0.5f; }
  else if (row < 2048) { const int li = row - 1024; rr = li >> 6; cc = li & 63; sy = 1.0f; sx = 0.25f; }
  else if (row < 3008) { const int li = row - 2048; rr = li / 40; cc = li - rr * 40; sy = 16.0f / 24.0f; sx = 0.4f; }
  else                 { const int li = row - 3008; rr = li / 24; cc = li - rr * 24; sy = 0.4f; sx = 16.0f / 24.0f; }
  float yc = fminf(fmaxf(((float)rr + 0.5f) * sy - 0.5f, 0.0f), 15.0f);
  const int y0 = (int)yc; const float fy = yc - (float)y0;
  const int y1 = y0 < 15 ? y0 + 1 : 15;
  float xc = fminf(fmaxf(((float)cc + 0.5f) * sx - 0.5f, 0.0f), 15.0f);
  const int x0 = (int)xc; const float fx = xc - (float)x0;
  const int x1 = x0 < 15 ? x0 + 1 : 15;
  const float w11 = fy * fx;
  const float w10 = fy - w11;
  const float w01 = fx - w11;
  const float w00 = 1.0f - fy - fx + w11;
  const float* p00 = pos + (size_t)(y0 * 16 + x0) * 1152 + dc;
  const float* p01 = pos + (size_t)(y0 * 16 + x1) * 1152 + dc;
  const float* p10 = pos + (size_t)(y1 * 16 + x0) * 1152 + dc;
  const float* p11 = pos + (size_t)(y1 * 16 + x1) * 1152 + dc;
  const float* bi  = bias + dc;
  short8 o;
#pragma unroll
  for (int j = 0; j < 8; ++j) {
    const float v = bi[j] + w00 * p00[j] + w01 * p01[j] + w10 * p10[j] + w11 * p11[j];
    o[j] = (short)f2bf(v);
  }
  *(short8*)(tab + (size_t)row * 1152 + dc) = o;
}

__device__ __forceinline__ void gload_lds16(const void* g, void* l) {
  __builtin_amdgcn_global_load_lds((__attribute__((address_space(1))) void*)g,
                                   (__attribute__((address_space(3))) void*)l, 16, 0, 0);
}

// ---------------- pass 2: r7 rhythm, 256x128 tile, 4 waves (2M x 2N), fb-reuse ----
// BK=32, 24 K-steps, 256 threads = 4 waves, wave-tile 128x64 (all rows in bounds:
// wn in {0,1} -> fb rows <= 127).  Per step per wave: 12 ds_read_b128 feed 32
// MFMA (fb[4] loaded once, reused across 8 M-frags) — 2x amortization of the
// per-step barrier/latency overhead vs r7's 8-read/16-MFMA.
// LDS 3 x (A 16KB + B 8KB) = 72 KB -> 2 blocks/CU; 2-ahead prefetch; counted
// vmcnt(12) steady (6 loads/thread/stage), tail 6 -> 0.
__global__ __launch_bounds__(256, 2) void gemm_kernel(
    const unsigned short* __restrict__ Abf, const unsigned short* __restrict__ Wbf,
    const unsigned short* __restrict__ tab, float* __restrict__ outp) {
  __shared__ __attribute__((aligned(16))) unsigned short As[3][256 * 32];  // 3 x 16 KB
  __shared__ __attribute__((aligned(16))) unsigned short Bs[3][128 * 32];  // 3 x 8 KB

  // grid 1116 = 124 m-tiles x 9 n-tiles; bijective XCD swizzle (q=139, r=4)
  const int bid = blockIdx.x;
  const int xcd = bid & 7, idx = bid >> 3;
  const int wgid = (xcd < 4 ? xcd * 140 : 560 + (xcd - 4) * 139) + idx;
  const int tm = wgid / 9, tn = wgid - tm * 9;
  const int m0 = tm * 256, n0 = tn * 128;

  const int tid = threadIdx.x;
  const int w = tid >> 6, lane = tid & 63;
  const int wm = w >> 1, wn = w & 1;        // 2M x 2N waves, wave-tile 128x64
  const int kg = lane >> 4, l15 = lane & 15;

  // staging lane map (r7-proven): row = base + (lane>>2), chunk = lane&3,
  // source chunk pre-swizzled by key (row>>1)&3 = (lane>>3)&3.
  const int srow = lane >> 2;
  const int schunk = ((lane & 3) ^ ((lane >> 3) & 3)) * 8;   // element offset
  // A: wave w covers rows w*64 .. w*64+63 (4 gloads of 16 rows)
  const unsigned short* Abase = Abf + (size_t)(m0 + w * 64 + srow) * K_TOT + schunk;
  // B: wave w covers rows w*32 .. w*32+31 (2 gloads)
  const unsigned short* Bbase = Wbf + (size_t)(n0 + w * 32 + srow) * K_TOT + schunk;

  const int rkey = (l15 >> 1) & 3;          // ds_read swizzle key (r7-proven)

  f32x4 acc[8][4] = {};

#define STAGE(p_, kt)                                                            \
  { const int k0_ = (kt) * 32;                                                   \
    gload_lds16(Abase + k0_,                      (char*)As[p_] + (w * 64) * 64);      \
    gload_lds16(Abase + (size_t)16 * K_TOT + k0_, (char*)As[p_] + (w * 64 + 16) * 64); \
    gload_lds16(Abase + (size_t)32 * K_TOT + k0_, (char*)As[p_] + (w * 64 + 32) * 64); \
    gload_lds16(Abase + (size_t)48 * K_TOT + k0_, (char*)As[p_] + (w * 64 + 48) * 64); \
    gload_lds16(Bbase + k0_,                      (char*)Bs[p_] + (w * 32) * 64);      \
    gload_lds16(Bbase + (size_t)16 * K_TOT + k0_, (char*)Bs[p_] + (w * 32 + 16) * 64); }

#define COMPUTE(p_)                                                              \
  { __builtin_amdgcn_s_setprio(1);                                               \
    short8 fb[4];                                                                \
    _Pragma("unroll") for (int n = 0; n < 4; ++n) {                              \
      const int br_ = wn * 64 + n * 16 + l15;                                    \
      fb[n] = *(const short8*)((const char*)Bs[p_] + br_ * 64 +                  \
                               ((kg ^ rkey) << 4));                              \
    }                                                                            \
    _Pragma("unroll") for (int i = 0; i < 8; ++i) {                              \
      const int ar_ = wm * 128 + i * 16 + l15;                                   \
      const short8 fa_ = *(const short8*)((const char*)As[p_] + ar_ * 64 +       \
                                          ((kg ^ rkey) << 4));                   \
      _Pragma("unroll") for (int n = 0; n < 4; ++n)                              \
        acc[i][n] = __builtin_amdgcn_mfma_f32_16x16x32_bf16(                     \
            fa_, fb[n], acc[i][n], 0, 0, 0);                                     \
    }                                                                            \
    __builtin_amdgcn_s_setprio(0); }

  // prologue: tiles 0,1 in flight (12 loads/thread)
  STAGE(0, 0)
  STAGE(1, 1)

#pragma unroll
  for (int t = 0; t < 24; ++t) {
    const int p = t % 3;
    if (t < 22) {
      STAGE((t + 2) % 3, t + 2)   // in-flight: t(6) t+1(6) t+2(6)
      asm volatile("s_waitcnt vmcnt(12)" ::: "memory");  // retire tile t only
    } else if (t == 22) {
      asm volatile("s_waitcnt vmcnt(6)" ::: "memory");
    } else {
      asm volatile("s_waitcnt vmcnt(0)" ::: "memory");
    }
    __builtin_amdgcn_s_barrier();   // tile t resident for all waves
    COMPUTE(p)
    __builtin_amdgcn_s_barrier();   // nobody re-stages buf p until all read it
  }

#undef STAGE
#undef COMPUTE

  // ---------------- epilogue (r5/r7-verified math): out = acc + tab[s%3968, d] ----
  const int s_base = m0 + wm * 128 + ((lane >> 4) << 2);  // + i*16 + r
  const int rem_base = s_base % CYC_ROWS;
  const int d_base = n0 + wn * 64 + l15;                  // + n*16

#pragma unroll
  for (int i = 0; i < 8; ++i) {
#pragma unroll
    for (int r = 0; r < 4; ++r) {
      const int off = i * 16 + r;
      int rem = rem_base + off;
      if (rem >= CYC_ROWS) rem -= CYC_ROWS;
      const unsigned short* trow = tab + (size_t)rem * 1152 + d_base;
      float* orow = outp + (size_t)(s_base + off) * 1152 + d_base;
#pragma unroll
      for (int n = 0; n < 4; ++n)
        orow[n * 16] = acc[i][n][r] + bf2f(trow[n * 16]);
    }
  }
}

extern "C" void kernel_launch(void* const* d_in, const int* in_sizes, int n_in,
                              void* d_out, int out_size, void* d_ws, size_t ws_size,
                              hipStream_t stream) {
  const float* A    = (const float*)d_in[0];  // seq_patches [31744,768]
  const float* W    = (const float*)d_in[1];  // w [1152,768]
  const float* bias = (const float*)d_in[2];  // b [1152]
  const float* pos  = (const float*)d_in[3];  // pos_emb [256,1152]
  unsigned short* Abf = (unsigned short*)d_ws;            // 48.76 MB
  unsigned short* Wbf = Abf + A_ELEMS;                    // +1.77 MB
  unsigned short* tab = Wbf + W_ELEMS;                    // +9.14 MB
  float* outp = (float*)d_out;

  cvt_kernel<<<12336, 256, 0, stream>>>(A, W, Abf);
  tab_kernel<<<2232, 256, 0, stream>>>(pos, bias, tab);
  gemm_kernel<<<1116, 256, 0, stream>>>(Abf, Wbf, tab, outp);
}